// Round 10
// baseline (508.471 us; speedup 1.0000x reference)
//
#include <hip/hip_runtime.h>
#include <hip/hip_bf16.h>
#include <hip/hip_fp16.h>

// Problem constants (match reference)
#define N_NODES 100000
#define N_EDGES 1600000
#define N_GRAPHS 128

// Counting-sort CSR build parameters
#define BSH 9                 // bucket = col >> 9
#define BNODES 512            // nodes per bucket
#define NB 196                // ceil(100000 / 512)
#define CAP 12288             // static per-bucket csr/record capacity (elems)
#define BLK 512               // histogram blocks
#define EPB (N_EDGES / BLK)   // 3125 edges per block (exact)
#define RECMAX 10240          // max records per bucket held in LDS

#define SPLIT 4               // pooling blocks per graph

// ---------------- CSR build (no global atomics) ----------------

__global__ __launch_bounds__(256) void k_hist(const int* __restrict__ col,
                                              int* __restrict__ hist_t) {
    __shared__ int h[NB];
    const int t = threadIdx.x, b = blockIdx.x;
    for (int i = t; i < NB; i += 256) h[i] = 0;
    __syncthreads();
    const int e0 = b * EPB;
    for (int i = t; i < EPB; i += 256) atomicAdd(&h[col[e0 + i] >> BSH], 1);
    __syncthreads();
    for (int i = t; i < NB; i += 256) hist_t[i * BLK + b] = h[i];
}

__global__ __launch_bounds__(512) void k_cursors(const int* __restrict__ hist_t,
                                                 int* __restrict__ cursors,
                                                 int* __restrict__ bcnt) {
    __shared__ int s[BLK];
    const int t = threadIdx.x, bin = blockIdx.x;
    const int v = hist_t[bin * BLK + t];
    s[t] = v; __syncthreads();
    for (int off = 1; off < BLK; off <<= 1) {
        int a = (t >= off) ? s[t - off] : 0;
        __syncthreads(); s[t] += a; __syncthreads();
    }
    cursors[bin * BLK + t] = bin * CAP + s[t] - v;   // exclusive + static base
    if (t == BLK - 1) bcnt[bin] = s[t];
}

__global__ __launch_bounds__(256) void k_mid(const int* __restrict__ row,
                                             const int* __restrict__ col,
                                             const int* __restrict__ cursors,
                                             int* __restrict__ bedges) {
    __shared__ int cur[NB];
    const int t = threadIdx.x, b = blockIdx.x;
    for (int i = t; i < NB; i += 256) cur[i] = cursors[i * BLK + b];
    __syncthreads();
    const int e0 = b * EPB;
    for (int i = t; i < EPB; i += 256) {
        const int c = col[e0 + i];
        const int r = row[e0 + i];
        const int pos = atomicAdd(&cur[c >> BSH], 1);
        bedges[pos] = r | ((c & (BNODES - 1)) << 17);   // row<2^17, lcol 9 bits
    }
}

__global__ __launch_bounds__(512) void k_build(const int* __restrict__ bedges,
                                               const int* __restrict__ bcnt,
                                               int* __restrict__ csr,
                                               int* __restrict__ offs,
                                               int* __restrict__ deg_c,
                                               float* __restrict__ dinv) {
    __shared__ int rec[RECMAX];
    __shared__ int deg[BNODES];
    __shared__ int offx[BNODES];
    __shared__ int cur[BNODES];
    const int t = threadIdx.x, bin = blockIdx.x;
    const int base = bin * CAP;
    const int cnt = bcnt[bin];
    const int vb = bin << BSH;
    const int nn = min(BNODES, N_NODES - vb);
    for (int i = t; i < cnt; i += 512) rec[i] = bedges[base + i];
    deg[t] = 0;
    __syncthreads();                 // all record loads done before any csr write
    for (int i = t; i < cnt; i += 512) atomicAdd(&deg[(rec[i] >> 17) & (BNODES - 1)], 1);
    __syncthreads();
    const int d = (t < nn) ? deg[t] : 0;
    const int pd = (d + 3) & ~3;     // pad each segment to x4
    offx[t] = pd; __syncthreads();
    for (int off = 1; off < BNODES; off <<= 1) {
        int a = (t >= off) ? offx[t - off] : 0;
        __syncthreads(); offx[t] += a; __syncthreads();
    }
    const int myoff = offx[t] - pd;  // exclusive
    cur[t] = myoff;
    if (t < nn) {
        offs[vb + t] = base + myoff;
        deg_c[vb + t] = d;
        dinv[vb + t] = (d > 0) ? rsqrtf((float)d) : 0.0f;
        for (int j = d; j < pd; j++) csr[base + myoff + j] = N_NODES;  // sentinel
    }
    __syncthreads();
    for (int i = t; i < cnt; i += 512) {
        const int r = rec[i];
        const int pos = atomicAdd(&cur[(r >> 17) & (BNODES - 1)], 1);
        csr[base + pos] = r & 0x1FFFF;
    }
}

// ---------------- register-tiled GEMM: H16[n] = fp16(dinv[n] * (X[n,:] @ W)) ----------------
// 128-node x 64-ch block tile, 256 threads, 4 nodes x 8 ch per thread.
// Per k per thread: 4 b32 X (bank-free, STR=66) + 2 b128 W (2-way free) + 32 FMA.

template <int CIN>
__global__ __launch_bounds__(256) void k_gemm(const float* __restrict__ X,
                                              const float* __restrict__ W,
                                              const float* __restrict__ dinv,
                                              __half* __restrict__ H16) {
    constexpr int STR = 66;                     // node-row stride (floats): 2 mod 4
    __shared__ float sX[128 * STR];             // [node][k-chunk] (~33.8 KB)
    __shared__ float sW[64 * 64];               // [k][c] (16 KB)
    const int t = threadIdx.x;
    const int nb = blockIdx.x * 128;
    const int tx = t & 7;                       // channel group: c0 = tx*8
    const int ty = t >> 3;                      // node group:    n0 = ty*4 (0..31)
    const int c0 = tx * 8, n0 = ty * 4;

    float acc[4][8] = {};

    for (int k0 = 0; k0 < CIN; k0 += 64) {
        if (k0) __syncthreads();
        // stage W chunk [64 x 64]
        for (int i = t; i < 64 * 16; i += 256) {
            const int k = i >> 4, c4 = (i & 15) * 4;
            *reinterpret_cast<float4*>(&sW[k * 64 + c4]) =
                *reinterpret_cast<const float4*>(W + (size_t)(k0 + k) * 64 + c4);
        }
        // stage X chunk [128 nodes x 64 k] via float2 writes (STR=66 keeps banks clean)
        for (int i = t; i < 128 * 16; i += 256) {
            const int node = i >> 4, k4 = (i & 15) * 4;
            const int gn = nb + node;
            float4 v = make_float4(0.f, 0.f, 0.f, 0.f);
            if (gn < N_NODES)
                v = *reinterpret_cast<const float4*>(X + (size_t)gn * CIN + k0 + k4);
            float* dst = &sX[node * STR + k4];
            *reinterpret_cast<float2*>(dst) = make_float2(v.x, v.y);
            *reinterpret_cast<float2*>(dst + 2) = make_float2(v.z, v.w);
        }
        __syncthreads();

        const float* xb = &sX[n0 * STR];
        #pragma unroll 4
        for (int k = 0; k < 64; k++) {
            const float4 b0 = *reinterpret_cast<const float4*>(&sW[k * 64 + c0]);
            const float4 b1 = *reinterpret_cast<const float4*>(&sW[k * 64 + c0 + 4]);
            const float a0 = xb[k];
            const float a1 = xb[STR + k];
            const float a2 = xb[2 * STR + k];
            const float a3 = xb[3 * STR + k];
            acc[0][0] += a0 * b0.x; acc[0][1] += a0 * b0.y; acc[0][2] += a0 * b0.z; acc[0][3] += a0 * b0.w;
            acc[0][4] += a0 * b1.x; acc[0][5] += a0 * b1.y; acc[0][6] += a0 * b1.z; acc[0][7] += a0 * b1.w;
            acc[1][0] += a1 * b0.x; acc[1][1] += a1 * b0.y; acc[1][2] += a1 * b0.z; acc[1][3] += a1 * b0.w;
            acc[1][4] += a1 * b1.x; acc[1][5] += a1 * b1.y; acc[1][6] += a1 * b1.z; acc[1][7] += a1 * b1.w;
            acc[2][0] += a2 * b0.x; acc[2][1] += a2 * b0.y; acc[2][2] += a2 * b0.z; acc[2][3] += a2 * b0.w;
            acc[2][4] += a2 * b1.x; acc[2][5] += a2 * b1.y; acc[2][6] += a2 * b1.z; acc[2][7] += a2 * b1.w;
            acc[3][0] += a3 * b0.x; acc[3][1] += a3 * b0.y; acc[3][2] += a3 * b0.z; acc[3][3] += a3 * b0.w;
            acc[3][4] += a3 * b1.x; acc[3][5] += a3 * b1.y; acc[3][6] += a3 * b1.z; acc[3][7] += a3 * b1.w;
        }
    }

    #pragma unroll
    for (int n = 0; n < 4; n++) {
        const int gn = nb + n0 + n;
        if (gn < N_NODES) {
            const float dv = dinv[gn];
            __half2 h[4];
            #pragma unroll
            for (int q = 0; q < 4; q++)
                h[q] = __floats2half2_rn(acc[n][2 * q] * dv, acc[n][2 * q + 1] * dv);
            *reinterpret_cast<int4*>(H16 + (size_t)gn * 64 + c0) =
                *reinterpret_cast<const int4*>(h);
        }
    }
}

// ---------------- propagation: Hout[v] = dinv[v] * sum_e fp32(H16[row_e]) + bias --------
// wave per node; lane = channel PAIR (half2); half-waves take even/odd edges.
// Segments padded to x4 (sentinel zero-row): 1 int4 CSR load per 4 edges.

__global__ __launch_bounds__(256) void k_prop(const __half* __restrict__ Hin,
                                              const int* __restrict__ csr,
                                              const int* __restrict__ offs,
                                              const int* __restrict__ deg_c,
                                              const float* __restrict__ dinv,
                                              const float* __restrict__ bias,
                                              float* __restrict__ Hout) {
    const int wave = threadIdx.x >> 6, lane = threadIdx.x & 63;
    const int v = blockIdx.x * 4 + wave;
    if (v >= N_NODES) return;
    const int c2 = lane & 31;              // channel pair: channels 2*c2, 2*c2+1
    const int half = lane >> 5;            // edge parity for this half-wave
    const int start = offs[v];             // multiple of 4 -> 16B aligned
    const int cntp = (deg_c[v] + 3) & ~3;
    const int* ep = csr + start;
    const __half* hb = Hin + c2 * 2;
    float ax = 0.f, ay = 0.f;
    for (int j = 0; j < cntp; j += 4) {
        const int4 q = *reinterpret_cast<const int4*>(ep + j);       // broadcast
        const int i0 = half ? q.y : q.x;
        const int i1 = half ? q.w : q.z;
        const __half2 h0 = *reinterpret_cast<const __half2*>(hb + (size_t)i0 * 64);
        const __half2 h1 = *reinterpret_cast<const __half2*>(hb + (size_t)i1 * 64);
        const float2 f0 = __half22float2(h0);
        const float2 f1 = __half22float2(h1);
        ax += f0.x + f1.x;
        ay += f0.y + f1.y;
    }
    // combine even/odd half-wave partials (lane ^ 32 holds the other parity)
    ax += __shfl_xor(ax, 32, 64);
    ay += __shfl_xor(ay, 32, 64);
    if (half == 0) {
        const float dv = dinv[v];
        float2 o;
        o.x = dv * ax + bias[c2 * 2];
        o.y = dv * ay + bias[c2 * 2 + 1];
        *reinterpret_cast<float2*>(Hout + (size_t)v * 64 + c2 * 2) = o;
    }
}

// ---------------- pooling: one (graph, split) block; atomic-free partials ----------------

__global__ __launch_bounds__(256) void k_pool(const float* __restrict__ H,
                                              const int* __restrict__ batch,
                                              float* __restrict__ partial) {
    const int g = blockIdx.x >> 2;           // graph
    const int s = blockIdx.x & (SPLIT - 1);  // split
    int lo = 0, hi = N_NODES;
    while (lo < hi) { int m = (lo + hi) >> 1; if (batch[m] < g) lo = m + 1; else hi = m; }
    const int a = lo;
    lo = 0; hi = N_NODES;
    while (lo < hi) { int m = (lo + hi) >> 1; if (batch[m] < g + 1) lo = m + 1; else hi = m; }
    const int b = lo;

    const int wave = threadIdx.x >> 6, lane = threadIdx.x & 63;
    const int lane16 = s * 4 + wave;         // 0..15: stride position
    float ac0 = 0.f, ac1 = 0.f, ac2 = 0.f, ac3 = 0.f;
    int v = a + lane16;
    for (; v + 48 < b; v += 64) {            // 4 independent loads in flight
        ac0 += H[(size_t)v * 64 + lane];
        ac1 += H[(size_t)(v + 16) * 64 + lane];
        ac2 += H[(size_t)(v + 32) * 64 + lane];
        ac3 += H[(size_t)(v + 48) * 64 + lane];
    }
    for (; v < b; v += 16) ac0 += H[(size_t)v * 64 + lane];
    const float acc = (ac0 + ac1) + (ac2 + ac3);

    __shared__ float red[4][64];
    red[wave][lane] = acc;
    __syncthreads();
    if (wave == 0) {
        const float r = (red[0][lane] + red[1][lane]) + (red[2][lane] + red[3][lane]);
        partial[((size_t)s * N_GRAPHS + g) * 64 + lane] = r;
    }
}

__global__ void k_final(const float* __restrict__ partial, const int* __restrict__ batch,
                        const float* __restrict__ Wl, const float* __restrict__ bl,
                        float* __restrict__ out) {
    __shared__ int scnt[128];
    int t = threadIdx.x;
    int lo = 0, hi = N_NODES;
    while (lo < hi) { int mid = (lo + hi) >> 1; if (batch[mid] < t) lo = mid + 1; else hi = mid; }
    int a = lo;
    lo = 0; hi = N_NODES;
    while (lo < hi) { int mid = (lo + hi) >> 1; if (batch[mid] < t + 1) lo = mid + 1; else hi = mid; }
    scnt[t] = lo - a;
    __syncthreads();
    for (int off = 64; off > 0; off >>= 1) {
        if (t < off) scnt[t] = max(scnt[t], scnt[t + off]);
        __syncthreads();
    }
    const float nmax = (float)scnt[0];
    float s = 0.f;
    for (int c = 0; c < 64; c++) {
        float g = 0.f;
        #pragma unroll
        for (int p = 0; p < SPLIT; p++)
            g += partial[((size_t)p * N_GRAPHS + t) * 64 + c];
        s += g * Wl[c];
    }
    out[t] = s / nmax + bl[0];
}

// ---------------- launch ----------------

extern "C" void kernel_launch(void* const* d_in, const int* in_sizes, int n_in,
                              void* d_out, int out_size, void* d_ws, size_t ws_size,
                              hipStream_t stream) {
    const float* x    = (const float*)d_in[0];
    const int*   ei   = (const int*)d_in[1];     // [2, E] int32
    const int*   batch= (const int*)d_in[2];
    const float* W1 = (const float*)d_in[3];  const float* b1 = (const float*)d_in[4];
    const float* W2 = (const float*)d_in[5];  const float* b2 = (const float*)d_in[6];
    const float* W3 = (const float*)d_in[7];  const float* b3 = (const float*)d_in[8];
    const float* W4 = (const float*)d_in[9];  const float* b4 = (const float*)d_in[10];
    const float* Wl = (const float*)d_in[11]; const float* bl = (const float*)d_in[12];
    float* out = (float*)d_out;

    const int* row = ei;
    const int* col = ei + N_EDGES;

    // workspace layout (256B aligned blocks)
    char* ws = (char*)d_ws;
    size_t off = 0;
    auto alloc = [&](size_t bytes) {
        void* p = ws + off;
        off = (off + bytes + 255) & ~(size_t)255;
        return p;
    };
    int*    hist_t  = (int*)alloc((size_t)NB * BLK * 4);
    int*    cursors = (int*)alloc((size_t)NB * BLK * 4);
    int*    bcnt    = (int*)alloc(NB * 4);
    int*    bedges  = (int*)alloc((size_t)NB * CAP * 4);   // aliased by csr
    int*    csr     = bedges;                              // in-place rebuild (safe)
    int*    offs    = (int*)alloc(N_NODES * 4);
    int*    deg_c   = (int*)alloc(N_NODES * 4);
    float*  dinv    = (float*)alloc(N_NODES * 4);
    __half* h16     = (__half*)alloc((size_t)(N_NODES + 1) * 64 * 2);  // fp16 gather table (+1 zero row)
    float*  h_b     = (float*)alloc((size_t)N_NODES * 64 * 4);         // fp32 prop output
    float*  partial = (float*)alloc((size_t)SPLIT * N_GRAPHS * 64 * 4);

    hipMemsetAsync(h16 + (size_t)N_NODES * 64, 0, 64 * 2, stream);   // zero sentinel row

    // CSR build: histogram -> cursors -> bucket scatter -> per-bucket build
    k_hist<<<BLK, 256, 0, stream>>>(col, hist_t);
    k_cursors<<<NB, 512, 0, stream>>>(hist_t, cursors, bcnt);
    k_mid<<<BLK, 256, 0, stream>>>(row, col, cursors, bedges);
    k_build<<<NB, 512, 0, stream>>>(bedges, bcnt, csr, offs, deg_c, dinv);

    const int GB = (N_NODES + 127) / 128;   // 782 gemm blocks

    // layer 1: h16 = fp16(dinv * (x @ W1)) ; h_b = dinv * prop(h16) + b1
    k_gemm<128><<<GB, 256, 0, stream>>>(x, W1, dinv, h16);
    k_prop<<<N_NODES / 4, 256, 0, stream>>>(h16, csr, offs, deg_c, dinv, b1, h_b);
    // layer 2
    k_gemm<64><<<GB, 256, 0, stream>>>(h_b, W2, dinv, h16);
    k_prop<<<N_NODES / 4, 256, 0, stream>>>(h16, csr, offs, deg_c, dinv, b2, h_b);
    // layer 3
    k_gemm<64><<<GB, 256, 0, stream>>>(h_b, W3, dinv, h16);
    k_prop<<<N_NODES / 4, 256, 0, stream>>>(h16, csr, offs, deg_c, dinv, b3, h_b);
    // layer 4
    k_gemm<64><<<GB, 256, 0, stream>>>(h_b, W4, dinv, h16);
    k_prop<<<N_NODES / 4, 256, 0, stream>>>(h16, csr, offs, deg_c, dinv, b4, h_b);

    // pooling + readout (atomic-free)
    k_pool<<<N_GRAPHS * SPLIT, 256, 0, stream>>>(h_b, batch, partial);
    k_final<<<1, 128, 0, stream>>>(partial, batch, Wl, bl, out);
}

// Round 11
// 407.219 us; speedup vs baseline: 1.2486x; 1.2486x over previous
//
#include <hip/hip_runtime.h>
#include <hip/hip_bf16.h>
#include <hip/hip_fp16.h>

// Problem constants (match reference)
#define N_NODES 100000
#define N_EDGES 1600000
#define N_GRAPHS 128

// Counting-sort CSR build parameters
#define BSH 9                 // bucket = col >> 9
#define BNODES 512            // nodes per bucket
#define NB 196                // ceil(100000 / 512)
#define CAP 12288             // static per-bucket csr/record capacity (elems)
#define BLK 512               // histogram blocks
#define EPB (N_EDGES / BLK)   // 3125 edges per block (exact)
#define RECMAX 10240          // max records per bucket held in LDS

#define SPLIT 4               // pooling blocks per graph

// ---------------- CSR build (no global atomics) ----------------

__global__ __launch_bounds__(256) void k_hist(const int* __restrict__ col,
                                              int* __restrict__ hist_t) {
    __shared__ int h[NB];
    const int t = threadIdx.x, b = blockIdx.x;
    for (int i = t; i < NB; i += 256) h[i] = 0;
    __syncthreads();
    const int e0 = b * EPB;
    for (int i = t; i < EPB; i += 256) atomicAdd(&h[col[e0 + i] >> BSH], 1);
    __syncthreads();
    for (int i = t; i < NB; i += 256) hist_t[i * BLK + b] = h[i];
}

__global__ __launch_bounds__(512) void k_cursors(const int* __restrict__ hist_t,
                                                 int* __restrict__ cursors,
                                                 int* __restrict__ bcnt) {
    __shared__ int s[BLK];
    const int t = threadIdx.x, bin = blockIdx.x;
    const int v = hist_t[bin * BLK + t];
    s[t] = v; __syncthreads();
    for (int off = 1; off < BLK; off <<= 1) {
        int a = (t >= off) ? s[t - off] : 0;
        __syncthreads(); s[t] += a; __syncthreads();
    }
    cursors[bin * BLK + t] = bin * CAP + s[t] - v;   // exclusive + static base
    if (t == BLK - 1) bcnt[bin] = s[t];
}

__global__ __launch_bounds__(256) void k_mid(const int* __restrict__ row,
                                             const int* __restrict__ col,
                                             const int* __restrict__ cursors,
                                             int* __restrict__ bedges) {
    __shared__ int cur[NB];
    const int t = threadIdx.x, b = blockIdx.x;
    for (int i = t; i < NB; i += 256) cur[i] = cursors[i * BLK + b];
    __syncthreads();
    const int e0 = b * EPB;
    for (int i = t; i < EPB; i += 256) {
        const int c = col[e0 + i];
        const int r = row[e0 + i];
        const int pos = atomicAdd(&cur[c >> BSH], 1);
        bedges[pos] = r | ((c & (BNODES - 1)) << 17);   // row<2^17, lcol 9 bits
    }
}

__global__ __launch_bounds__(512) void k_build(const int* __restrict__ bedges,
                                               const int* __restrict__ bcnt,
                                               int* __restrict__ csr,
                                               int* __restrict__ offs,
                                               int* __restrict__ deg_c,
                                               float* __restrict__ dinv) {
    __shared__ int rec[RECMAX];
    __shared__ int deg[BNODES];
    __shared__ int offx[BNODES];
    __shared__ int cur[BNODES];
    const int t = threadIdx.x, bin = blockIdx.x;
    const int base = bin * CAP;
    const int cnt = bcnt[bin];
    const int vb = bin << BSH;
    const int nn = min(BNODES, N_NODES - vb);
    for (int i = t; i < cnt; i += 512) rec[i] = bedges[base + i];
    deg[t] = 0;
    __syncthreads();                 // all record loads done before any csr write
    for (int i = t; i < cnt; i += 512) atomicAdd(&deg[(rec[i] >> 17) & (BNODES - 1)], 1);
    __syncthreads();
    const int d = (t < nn) ? deg[t] : 0;
    const int pd = (d + 7) & ~7;     // pad each segment to x8 (MLP in k_prop)
    offx[t] = pd; __syncthreads();
    for (int off = 1; off < BNODES; off <<= 1) {
        int a = (t >= off) ? offx[t - off] : 0;
        __syncthreads(); offx[t] += a; __syncthreads();
    }
    const int myoff = offx[t] - pd;  // exclusive
    cur[t] = myoff;
    if (t < nn) {
        offs[vb + t] = base + myoff;
        deg_c[vb + t] = d;
        dinv[vb + t] = (d > 0) ? rsqrtf((float)d) : 0.0f;
        for (int j = d; j < pd; j++) csr[base + myoff + j] = N_NODES;  // sentinel
    }
    __syncthreads();
    for (int i = t; i < cnt; i += 512) {
        const int r = rec[i];
        const int pos = atomicAdd(&cur[(r >> 17) & (BNODES - 1)], 1);
        csr[base + pos] = r & 0x1FFFF;
    }
}

// ---------------- register-tiled GEMM: H16[n] = fp16(dinv[n] * (X[n,:] @ W)) ----------------
// 128-node x 64-ch block tile, 256 threads, 4 nodes x 8 ch per thread.

template <int CIN>
__global__ __launch_bounds__(256) void k_gemm(const float* __restrict__ X,
                                              const float* __restrict__ W,
                                              const float* __restrict__ dinv,
                                              __half* __restrict__ H16) {
    constexpr int STR = 66;                     // node-row stride (floats): 2 mod 4
    __shared__ float sX[128 * STR];             // [node][k-chunk] (~33.8 KB)
    __shared__ float sW[64 * 64];               // [k][c] (16 KB)
    const int t = threadIdx.x;
    const int nb = blockIdx.x * 128;
    const int tx = t & 7;                       // channel group: c0 = tx*8
    const int ty = t >> 3;                      // node group:    n0 = ty*4 (0..31)
    const int c0 = tx * 8, n0 = ty * 4;

    float acc[4][8] = {};

    for (int k0 = 0; k0 < CIN; k0 += 64) {
        if (k0) __syncthreads();
        for (int i = t; i < 64 * 16; i += 256) {
            const int k = i >> 4, c4 = (i & 15) * 4;
            *reinterpret_cast<float4*>(&sW[k * 64 + c4]) =
                *reinterpret_cast<const float4*>(W + (size_t)(k0 + k) * 64 + c4);
        }
        for (int i = t; i < 128 * 16; i += 256) {
            const int node = i >> 4, k4 = (i & 15) * 4;
            const int gn = nb + node;
            float4 v = make_float4(0.f, 0.f, 0.f, 0.f);
            if (gn < N_NODES)
                v = *reinterpret_cast<const float4*>(X + (size_t)gn * CIN + k0 + k4);
            float* dst = &sX[node * STR + k4];
            *reinterpret_cast<float2*>(dst) = make_float2(v.x, v.y);
            *reinterpret_cast<float2*>(dst + 2) = make_float2(v.z, v.w);
        }
        __syncthreads();

        const float* xb = &sX[n0 * STR];
        #pragma unroll 4
        for (int k = 0; k < 64; k++) {
            const float4 b0 = *reinterpret_cast<const float4*>(&sW[k * 64 + c0]);
            const float4 b1 = *reinterpret_cast<const float4*>(&sW[k * 64 + c0 + 4]);
            const float a0 = xb[k];
            const float a1 = xb[STR + k];
            const float a2 = xb[2 * STR + k];
            const float a3 = xb[3 * STR + k];
            acc[0][0] += a0 * b0.x; acc[0][1] += a0 * b0.y; acc[0][2] += a0 * b0.z; acc[0][3] += a0 * b0.w;
            acc[0][4] += a0 * b1.x; acc[0][5] += a0 * b1.y; acc[0][6] += a0 * b1.z; acc[0][7] += a0 * b1.w;
            acc[1][0] += a1 * b0.x; acc[1][1] += a1 * b0.y; acc[1][2] += a1 * b0.z; acc[1][3] += a1 * b0.w;
            acc[1][4] += a1 * b1.x; acc[1][5] += a1 * b1.y; acc[1][6] += a1 * b1.z; acc[1][7] += a1 * b1.w;
            acc[2][0] += a2 * b0.x; acc[2][1] += a2 * b0.y; acc[2][2] += a2 * b0.z; acc[2][3] += a2 * b0.w;
            acc[2][4] += a2 * b1.x; acc[2][5] += a2 * b1.y; acc[2][6] += a2 * b1.z; acc[2][7] += a2 * b1.w;
            acc[3][0] += a3 * b0.x; acc[3][1] += a3 * b0.y; acc[3][2] += a3 * b0.z; acc[3][3] += a3 * b0.w;
            acc[3][4] += a3 * b1.x; acc[3][5] += a3 * b1.y; acc[3][6] += a3 * b1.z; acc[3][7] += a3 * b1.w;
        }
    }

    #pragma unroll
    for (int n = 0; n < 4; n++) {
        const int gn = nb + n0 + n;
        if (gn < N_NODES) {
            const float dv = dinv[gn];
            __half2 h[4];
            #pragma unroll
            for (int q = 0; q < 4; q++)
                h[q] = __floats2half2_rn(acc[n][2 * q] * dv, acc[n][2 * q + 1] * dv);
            *reinterpret_cast<int4*>(H16 + (size_t)gn * 64 + c0) =
                *reinterpret_cast<const int4*>(h);
        }
    }
}

// ---------------- propagation: Hout[v] = dinv[v] * sum_e fp32(H16[row_e]) + bias --------
// ONE NODE PER HALF-WAVE: lanes 0-31 own node A (32 half2 channel pairs),
// lanes 32-63 own node B. Per iteration each half-wave covers 8 of its own
// edges -> 8 independent gather instructions in flight per wave (2x R9).

__global__ __launch_bounds__(256) void k_prop(const __half* __restrict__ Hin,
                                              const int* __restrict__ csr,
                                              const int* __restrict__ offs,
                                              const int* __restrict__ deg_c,
                                              const float* __restrict__ dinv,
                                              const float* __restrict__ bias,
                                              float* __restrict__ Hout) {
    const int wave = threadIdx.x >> 6, lane = threadIdx.x & 63;
    const int half = lane >> 5;            // which node this half-wave owns
    const int c2 = lane & 31;              // channel pair: channels 2*c2, 2*c2+1
    const int v = (blockIdx.x * 4 + wave) * 2 + half;   // grid sized so v < N_NODES
    const int start = offs[v];             // multiple of 8 -> 32B aligned
    const int cntp = (deg_c[v] + 7) & ~7;
    const int* ep = csr + start;
    const __half* hb = Hin + c2 * 2;
    float ax = 0.f, ay = 0.f;
    for (int j = 0; j < cntp; j += 8) {
        const int4 q0 = *reinterpret_cast<const int4*>(ep + j);      // per-half-wave
        const int4 q1 = *reinterpret_cast<const int4*>(ep + j + 4);
        const float2 f0 = __half22float2(*reinterpret_cast<const __half2*>(hb + (size_t)q0.x * 64));
        const float2 f1 = __half22float2(*reinterpret_cast<const __half2*>(hb + (size_t)q0.y * 64));
        const float2 f2 = __half22float2(*reinterpret_cast<const __half2*>(hb + (size_t)q0.z * 64));
        const float2 f3 = __half22float2(*reinterpret_cast<const __half2*>(hb + (size_t)q0.w * 64));
        const float2 f4 = __half22float2(*reinterpret_cast<const __half2*>(hb + (size_t)q1.x * 64));
        const float2 f5 = __half22float2(*reinterpret_cast<const __half2*>(hb + (size_t)q1.y * 64));
        const float2 f6 = __half22float2(*reinterpret_cast<const __half2*>(hb + (size_t)q1.z * 64));
        const float2 f7 = __half22float2(*reinterpret_cast<const __half2*>(hb + (size_t)q1.w * 64));
        ax += ((f0.x + f1.x) + (f2.x + f3.x)) + ((f4.x + f5.x) + (f6.x + f7.x));
        ay += ((f0.y + f1.y) + (f2.y + f3.y)) + ((f4.y + f5.y) + (f6.y + f7.y));
    }
    const float dv = dinv[v];
    float2 o;
    o.x = dv * ax + bias[c2 * 2];
    o.y = dv * ay + bias[c2 * 2 + 1];
    *reinterpret_cast<float2*>(Hout + (size_t)v * 64 + c2 * 2) = o;
}

// ---------------- pooling: one (graph, split) block; atomic-free partials ----------------

__global__ __launch_bounds__(256) void k_pool(const float* __restrict__ H,
                                              const int* __restrict__ batch,
                                              float* __restrict__ partial) {
    const int g = blockIdx.x >> 2;           // graph
    const int s = blockIdx.x & (SPLIT - 1);  // split
    int lo = 0, hi = N_NODES;
    while (lo < hi) { int m = (lo + hi) >> 1; if (batch[m] < g) lo = m + 1; else hi = m; }
    const int a = lo;
    lo = 0; hi = N_NODES;
    while (lo < hi) { int m = (lo + hi) >> 1; if (batch[m] < g + 1) lo = m + 1; else hi = m; }
    const int b = lo;

    const int wave = threadIdx.x >> 6, lane = threadIdx.x & 63;
    const int lane16 = s * 4 + wave;         // 0..15: stride position
    float ac0 = 0.f, ac1 = 0.f, ac2 = 0.f, ac3 = 0.f;
    int v = a + lane16;
    for (; v + 48 < b; v += 64) {            // 4 independent loads in flight
        ac0 += H[(size_t)v * 64 + lane];
        ac1 += H[(size_t)(v + 16) * 64 + lane];
        ac2 += H[(size_t)(v + 32) * 64 + lane];
        ac3 += H[(size_t)(v + 48) * 64 + lane];
    }
    for (; v < b; v += 16) ac0 += H[(size_t)v * 64 + lane];
    const float acc = (ac0 + ac1) + (ac2 + ac3);

    __shared__ float red[4][64];
    red[wave][lane] = acc;
    __syncthreads();
    if (wave == 0) {
        const float r = (red[0][lane] + red[1][lane]) + (red[2][lane] + red[3][lane]);
        partial[((size_t)s * N_GRAPHS + g) * 64 + lane] = r;
    }
}

__global__ void k_final(const float* __restrict__ partial, const int* __restrict__ batch,
                        const float* __restrict__ Wl, const float* __restrict__ bl,
                        float* __restrict__ out) {
    __shared__ int scnt[128];
    int t = threadIdx.x;
    int lo = 0, hi = N_NODES;
    while (lo < hi) { int mid = (lo + hi) >> 1; if (batch[mid] < t) lo = mid + 1; else hi = mid; }
    int a = lo;
    lo = 0; hi = N_NODES;
    while (lo < hi) { int mid = (lo + hi) >> 1; if (batch[mid] < t + 1) lo = mid + 1; else hi = mid; }
    scnt[t] = lo - a;
    __syncthreads();
    for (int off = 64; off > 0; off >>= 1) {
        if (t < off) scnt[t] = max(scnt[t], scnt[t + off]);
        __syncthreads();
    }
    const float nmax = (float)scnt[0];
    float s = 0.f;
    for (int c = 0; c < 64; c++) {
        float g = 0.f;
        #pragma unroll
        for (int p = 0; p < SPLIT; p++)
            g += partial[((size_t)p * N_GRAPHS + t) * 64 + c];
        s += g * Wl[c];
    }
    out[t] = s / nmax + bl[0];
}

// ---------------- launch ----------------

extern "C" void kernel_launch(void* const* d_in, const int* in_sizes, int n_in,
                              void* d_out, int out_size, void* d_ws, size_t ws_size,
                              hipStream_t stream) {
    const float* x    = (const float*)d_in[0];
    const int*   ei   = (const int*)d_in[1];     // [2, E] int32
    const int*   batch= (const int*)d_in[2];
    const float* W1 = (const float*)d_in[3];  const float* b1 = (const float*)d_in[4];
    const float* W2 = (const float*)d_in[5];  const float* b2 = (const float*)d_in[6];
    const float* W3 = (const float*)d_in[7];  const float* b3 = (const float*)d_in[8];
    const float* W4 = (const float*)d_in[9];  const float* b4 = (const float*)d_in[10];
    const float* Wl = (const float*)d_in[11]; const float* bl = (const float*)d_in[12];
    float* out = (float*)d_out;

    const int* row = ei;
    const int* col = ei + N_EDGES;

    // workspace layout (256B aligned blocks)
    char* ws = (char*)d_ws;
    size_t off = 0;
    auto alloc = [&](size_t bytes) {
        void* p = ws + off;
        off = (off + bytes + 255) & ~(size_t)255;
        return p;
    };
    int*    hist_t  = (int*)alloc((size_t)NB * BLK * 4);
    int*    cursors = (int*)alloc((size_t)NB * BLK * 4);
    int*    bcnt    = (int*)alloc(NB * 4);
    int*    bedges  = (int*)alloc((size_t)NB * CAP * 4);   // aliased by csr
    int*    csr     = bedges;                              // in-place rebuild (safe)
    int*    offs    = (int*)alloc(N_NODES * 4);
    int*    deg_c   = (int*)alloc(N_NODES * 4);
    float*  dinv    = (float*)alloc(N_NODES * 4);
    __half* h16     = (__half*)alloc((size_t)(N_NODES + 1) * 64 * 2);  // fp16 gather table (+1 zero row)
    float*  h_b     = (float*)alloc((size_t)N_NODES * 64 * 4);         // fp32 prop output
    float*  partial = (float*)alloc((size_t)SPLIT * N_GRAPHS * 64 * 4);

    hipMemsetAsync(h16 + (size_t)N_NODES * 64, 0, 64 * 2, stream);   // zero sentinel row

    // CSR build: histogram -> cursors -> bucket scatter -> per-bucket build
    k_hist<<<BLK, 256, 0, stream>>>(col, hist_t);
    k_cursors<<<NB, 512, 0, stream>>>(hist_t, cursors, bcnt);
    k_mid<<<BLK, 256, 0, stream>>>(row, col, cursors, bedges);
    k_build<<<NB, 512, 0, stream>>>(bedges, bcnt, csr, offs, deg_c, dinv);

    const int GB = (N_NODES + 127) / 128;   // 782 gemm blocks
    const int PB = N_NODES / 8;             // 12500 prop blocks (8 nodes/block)

    // layer 1: h16 = fp16(dinv * (x @ W1)) ; h_b = dinv * prop(h16) + b1
    k_gemm<128><<<GB, 256, 0, stream>>>(x, W1, dinv, h16);
    k_prop<<<PB, 256, 0, stream>>>(h16, csr, offs, deg_c, dinv, b1, h_b);
    // layer 2
    k_gemm<64><<<GB, 256, 0, stream>>>(h_b, W2, dinv, h16);
    k_prop<<<PB, 256, 0, stream>>>(h16, csr, offs, deg_c, dinv, b2, h_b);
    // layer 3
    k_gemm<64><<<GB, 256, 0, stream>>>(h_b, W3, dinv, h16);
    k_prop<<<PB, 256, 0, stream>>>(h16, csr, offs, deg_c, dinv, b3, h_b);
    // layer 4
    k_gemm<64><<<GB, 256, 0, stream>>>(h_b, W4, dinv, h16);
    k_prop<<<PB, 256, 0, stream>>>(h16, csr, offs, deg_c, dinv, b4, h_b);

    // pooling + readout (atomic-free)
    k_pool<<<N_GRAPHS * SPLIT, 256, 0, stream>>>(h_b, batch, partial);
    k_final<<<1, 128, 0, stream>>>(partial, batch, Wl, bl, out);
}

// Round 12
// 367.252 us; speedup vs baseline: 1.3845x; 1.1088x over previous
//
#include <hip/hip_runtime.h>
#include <hip/hip_bf16.h>
#include <hip/hip_fp16.h>

// Problem constants (match reference)
#define N_NODES 100000
#define N_EDGES 1600000
#define N_GRAPHS 128

// Counting-sort CSR build parameters
#define BSH 9                 // bucket = col >> 9
#define BNODES 512            // nodes per bucket
#define NB 196                // ceil(100000 / 512)
#define CAP 12288             // static per-bucket csr/record capacity (elems)
#define BLK 512               // histogram blocks
#define EPB (N_EDGES / BLK)   // 3125 edges per block (exact)
#define RECMAX 10240          // max records per bucket held in LDS

#define SPLIT 4               // pooling blocks per graph

typedef __attribute__((ext_vector_type(8))) _Float16 v8h;
typedef __attribute__((ext_vector_type(4))) float v4f;

// ---------------- CSR build (no global atomics) ----------------

__global__ __launch_bounds__(256) void k_hist(const int* __restrict__ col,
                                              int* __restrict__ hist_t) {
    __shared__ int h[NB];
    const int t = threadIdx.x, b = blockIdx.x;
    for (int i = t; i < NB; i += 256) h[i] = 0;
    __syncthreads();
    const int e0 = b * EPB;
    for (int i = t; i < EPB; i += 256) atomicAdd(&h[col[e0 + i] >> BSH], 1);
    __syncthreads();
    for (int i = t; i < NB; i += 256) hist_t[i * BLK + b] = h[i];
}

__global__ __launch_bounds__(512) void k_cursors(const int* __restrict__ hist_t,
                                                 int* __restrict__ cursors,
                                                 int* __restrict__ bcnt) {
    __shared__ int s[BLK];
    const int t = threadIdx.x, bin = blockIdx.x;
    const int v = hist_t[bin * BLK + t];
    s[t] = v; __syncthreads();
    for (int off = 1; off < BLK; off <<= 1) {
        int a = (t >= off) ? s[t - off] : 0;
        __syncthreads(); s[t] += a; __syncthreads();
    }
    cursors[bin * BLK + t] = bin * CAP + s[t] - v;   // exclusive + static base
    if (t == BLK - 1) bcnt[bin] = s[t];
}

__global__ __launch_bounds__(256) void k_mid(const int* __restrict__ row,
                                             const int* __restrict__ col,
                                             const int* __restrict__ cursors,
                                             int* __restrict__ bedges) {
    __shared__ int cur[NB];
    const int t = threadIdx.x, b = blockIdx.x;
    for (int i = t; i < NB; i += 256) cur[i] = cursors[i * BLK + b];
    __syncthreads();
    const int e0 = b * EPB;
    for (int i = t; i < EPB; i += 256) {
        const int c = col[e0 + i];
        const int r = row[e0 + i];
        const int pos = atomicAdd(&cur[c >> BSH], 1);
        bedges[pos] = r | ((c & (BNODES - 1)) << 17);   // row<2^17, lcol 9 bits
    }
}

__global__ __launch_bounds__(512) void k_build(const int* __restrict__ bedges,
                                               const int* __restrict__ bcnt,
                                               int* __restrict__ csr,
                                               int* __restrict__ offs,
                                               int* __restrict__ deg_c,
                                               float* __restrict__ dinv) {
    __shared__ int rec[RECMAX];
    __shared__ int deg[BNODES];
    __shared__ int offx[BNODES];
    __shared__ int cur[BNODES];
    const int t = threadIdx.x, bin = blockIdx.x;
    const int base = bin * CAP;
    const int cnt = bcnt[bin];
    const int vb = bin << BSH;
    const int nn = min(BNODES, N_NODES - vb);
    for (int i = t; i < cnt; i += 512) rec[i] = bedges[base + i];
    deg[t] = 0;
    __syncthreads();                 // all record loads done before any csr write
    for (int i = t; i < cnt; i += 512) atomicAdd(&deg[(rec[i] >> 17) & (BNODES - 1)], 1);
    __syncthreads();
    const int d = (t < nn) ? deg[t] : 0;
    const int pd = (d + 7) & ~7;     // pad each segment to x8 (MLP in k_prop)
    offx[t] = pd; __syncthreads();
    for (int off = 1; off < BNODES; off <<= 1) {
        int a = (t >= off) ? offx[t - off] : 0;
        __syncthreads(); offx[t] += a; __syncthreads();
    }
    const int myoff = offx[t] - pd;  // exclusive
    cur[t] = myoff;
    if (t < nn) {
        offs[vb + t] = base + myoff;
        deg_c[vb + t] = d;
        dinv[vb + t] = (d > 0) ? rsqrtf((float)d) : 0.0f;
        for (int j = d; j < pd; j++) csr[base + myoff + j] = N_NODES;  // sentinel
    }
    __syncthreads();
    for (int i = t; i < cnt; i += 512) {
        const int r = rec[i];
        const int pos = atomicAdd(&cur[(r >> 17) & (BNODES - 1)], 1);
        csr[base + pos] = r & 0x1FFFF;
    }
}

// ---------------- MFMA GEMM: H16[n] = fp16(dinv[n] * (X[n,:] @ W)) ----------------
// 128-node x 64-ch block tile, 4 waves; wave owns 32 nodes (2 m-tiles) x 64 ch
// (4 n-tiles). fp16 inputs, fp32 accumulate; W split hi+lo fp16 so weight
// rounding is ~exact — only the A-input rounding (2.4e-4 rel) is added.
// Layouts (guide-verified): A[m=lane&15][k=quad*8+j]; B via transposed LDS
// (k-contiguous per channel); C/D col=lane&15, row=quad*4+reg.

template <int CIN>
__global__ __launch_bounds__(256) void k_gemm(const float* __restrict__ X,
                                              const float* __restrict__ W,
                                              const float* __restrict__ dinv,
                                              __half* __restrict__ H16) {
    constexpr int SA = 72;                       // halves per node row (pad 8)
    constexpr int SB = 72;
    __shared__ __align__(16) _Float16 sA[128 * SA];   // 18.4 KB
    __shared__ __align__(16) _Float16 sBh[64 * SB];   // 9.2 KB
    __shared__ __align__(16) _Float16 sBl[64 * SB];   // 9.2 KB
    const int t = threadIdx.x;
    const int w = t >> 6, lane = t & 63;
    const int quad = lane >> 4, l16 = lane & 15;
    const int nb = blockIdx.x * 128;

    v4f acc[2][4] = {};   // [mtile][ntile]

    for (int k0 = 0; k0 < CIN; k0 += 64) {
        if (k0) __syncthreads();
        // stage W chunk [64k x 64c] -> transposed hi/lo [c][k]
        for (int i = t; i < 64 * 16; i += 256) {
            const int k = i >> 4, c4 = (i & 15) * 4;
            const float4 wv = *reinterpret_cast<const float4*>(W + (size_t)(k0 + k) * 64 + c4);
            const float wf[4] = {wv.x, wv.y, wv.z, wv.w};
            #pragma unroll
            for (int j = 0; j < 4; j++) {
                const _Float16 hi = (_Float16)wf[j];
                sBh[(c4 + j) * SB + k] = hi;
                sBl[(c4 + j) * SB + k] = (_Float16)(wf[j] - (float)hi);
            }
        }
        // stage X chunk [128 nodes x 64k] fp32 -> fp16, coalesced float4 reads
        for (int i = t; i < 128 * 16; i += 256) {
            const int node = i >> 4, k4 = (i & 15) * 4;
            const int gn = nb + node;
            float4 v = make_float4(0.f, 0.f, 0.f, 0.f);
            if (gn < N_NODES)
                v = *reinterpret_cast<const float4*>(X + (size_t)gn * CIN + k0 + k4);
            _Float16* d = &sA[node * SA + k4];
            d[0] = (_Float16)v.x; d[1] = (_Float16)v.y;
            d[2] = (_Float16)v.z; d[3] = (_Float16)v.w;
        }
        __syncthreads();

        #pragma unroll
        for (int kt = 0; kt < 2; kt++) {
            const int kb = kt * 32 + quad * 8;
            v8h afr[2], bh[4], bl[4];
            #pragma unroll
            for (int mt = 0; mt < 2; mt++)
                afr[mt] = *reinterpret_cast<const v8h*>(&sA[(w * 32 + mt * 16 + l16) * SA + kb]);
            #pragma unroll
            for (int nt = 0; nt < 4; nt++) {
                bh[nt] = *reinterpret_cast<const v8h*>(&sBh[(nt * 16 + l16) * SB + kb]);
                bl[nt] = *reinterpret_cast<const v8h*>(&sBl[(nt * 16 + l16) * SB + kb]);
            }
            #pragma unroll
            for (int mt = 0; mt < 2; mt++)
                #pragma unroll
                for (int nt = 0; nt < 4; nt++) {
                    acc[mt][nt] = __builtin_amdgcn_mfma_f32_16x16x32_f16(afr[mt], bh[nt], acc[mt][nt], 0, 0, 0);
                    acc[mt][nt] = __builtin_amdgcn_mfma_f32_16x16x32_f16(afr[mt], bl[nt], acc[mt][nt], 0, 0, 0);
                }
        }
    }

    // epilogue: D row = quad*4+reg, col = l16; node = nb + w*32 + mt*16 + row
    #pragma unroll
    for (int mt = 0; mt < 2; mt++) {
        #pragma unroll
        for (int reg = 0; reg < 4; reg++) {
            const int node = nb + w * 32 + mt * 16 + quad * 4 + reg;
            if (node < N_NODES) {
                const float dv = dinv[node];
                #pragma unroll
                for (int nt = 0; nt < 4; nt++)
                    H16[(size_t)node * 64 + nt * 16 + l16] =
                        __float2half(acc[mt][nt][reg] * dv);
            }
        }
    }
}

// ---------------- propagation: Hout[v] = dinv[v] * sum_e fp32(H16[row_e]) + bias --------
// ONE NODE PER HALF-WAVE: 8 independent gather instructions in flight per wave.

__global__ __launch_bounds__(256) void k_prop(const __half* __restrict__ Hin,
                                              const int* __restrict__ csr,
                                              const int* __restrict__ offs,
                                              const int* __restrict__ deg_c,
                                              const float* __restrict__ dinv,
                                              const float* __restrict__ bias,
                                              float* __restrict__ Hout) {
    const int wave = threadIdx.x >> 6, lane = threadIdx.x & 63;
    const int half = lane >> 5;            // which node this half-wave owns
    const int c2 = lane & 31;              // channel pair: channels 2*c2, 2*c2+1
    const int v = (blockIdx.x * 4 + wave) * 2 + half;   // grid sized so v < N_NODES
    const int start = offs[v];             // multiple of 8 -> 32B aligned
    const int cntp = (deg_c[v] + 7) & ~7;
    const int* ep = csr + start;
    const __half* hb = Hin + c2 * 2;
    float ax = 0.f, ay = 0.f;
    for (int j = 0; j < cntp; j += 8) {
        const int4 q0 = *reinterpret_cast<const int4*>(ep + j);      // per-half-wave
        const int4 q1 = *reinterpret_cast<const int4*>(ep + j + 4);
        const float2 f0 = __half22float2(*reinterpret_cast<const __half2*>(hb + (size_t)q0.x * 64));
        const float2 f1 = __half22float2(*reinterpret_cast<const __half2*>(hb + (size_t)q0.y * 64));
        const float2 f2 = __half22float2(*reinterpret_cast<const __half2*>(hb + (size_t)q0.z * 64));
        const float2 f3 = __half22float2(*reinterpret_cast<const __half2*>(hb + (size_t)q0.w * 64));
        const float2 f4 = __half22float2(*reinterpret_cast<const __half2*>(hb + (size_t)q1.x * 64));
        const float2 f5 = __half22float2(*reinterpret_cast<const __half2*>(hb + (size_t)q1.y * 64));
        const float2 f6 = __half22float2(*reinterpret_cast<const __half2*>(hb + (size_t)q1.z * 64));
        const float2 f7 = __half22float2(*reinterpret_cast<const __half2*>(hb + (size_t)q1.w * 64));
        ax += ((f0.x + f1.x) + (f2.x + f3.x)) + ((f4.x + f5.x) + (f6.x + f7.x));
        ay += ((f0.y + f1.y) + (f2.y + f3.y)) + ((f4.y + f5.y) + (f6.y + f7.y));
    }
    const float dv = dinv[v];
    float2 o;
    o.x = dv * ax + bias[c2 * 2];
    o.y = dv * ay + bias[c2 * 2 + 1];
    *reinterpret_cast<float2*>(Hout + (size_t)v * 64 + c2 * 2) = o;
}

// ---------------- pooling: one (graph, split) block; atomic-free partials ----------------

__global__ __launch_bounds__(256) void k_pool(const float* __restrict__ H,
                                              const int* __restrict__ batch,
                                              float* __restrict__ partial) {
    const int g = blockIdx.x >> 2;           // graph
    const int s = blockIdx.x & (SPLIT - 1);  // split
    int lo = 0, hi = N_NODES;
    while (lo < hi) { int m = (lo + hi) >> 1; if (batch[m] < g) lo = m + 1; else hi = m; }
    const int a = lo;
    lo = 0; hi = N_NODES;
    while (lo < hi) { int m = (lo + hi) >> 1; if (batch[m] < g + 1) lo = m + 1; else hi = m; }
    const int b = lo;

    const int wave = threadIdx.x >> 6, lane = threadIdx.x & 63;
    const int lane16 = s * 4 + wave;         // 0..15: stride position
    float ac0 = 0.f, ac1 = 0.f, ac2 = 0.f, ac3 = 0.f;
    int v = a + lane16;
    for (; v + 48 < b; v += 64) {            // 4 independent loads in flight
        ac0 += H[(size_t)v * 64 + lane];
        ac1 += H[(size_t)(v + 16) * 64 + lane];
        ac2 += H[(size_t)(v + 32) * 64 + lane];
        ac3 += H[(size_t)(v + 48) * 64 + lane];
    }
    for (; v < b; v += 16) ac0 += H[(size_t)v * 64 + lane];
    const float acc = (ac0 + ac1) + (ac2 + ac3);

    __shared__ float red[4][64];
    red[wave][lane] = acc;
    __syncthreads();
    if (wave == 0) {
        const float r = (red[0][lane] + red[1][lane]) + (red[2][lane] + red[3][lane]);
        partial[((size_t)s * N_GRAPHS + g) * 64 + lane] = r;
    }
}

__global__ void k_final(const float* __restrict__ partial, const int* __restrict__ batch,
                        const float* __restrict__ Wl, const float* __restrict__ bl,
                        float* __restrict__ out) {
    __shared__ int scnt[128];
    int t = threadIdx.x;
    int lo = 0, hi = N_NODES;
    while (lo < hi) { int mid = (lo + hi) >> 1; if (batch[mid] < t) lo = mid + 1; else hi = mid; }
    int a = lo;
    lo = 0; hi = N_NODES;
    while (lo < hi) { int mid = (lo + hi) >> 1; if (batch[mid] < t + 1) lo = mid + 1; else hi = mid; }
    scnt[t] = lo - a;
    __syncthreads();
    for (int off = 64; off > 0; off >>= 1) {
        if (t < off) scnt[t] = max(scnt[t], scnt[t + off]);
        __syncthreads();
    }
    const float nmax = (float)scnt[0];
    float s = 0.f;
    for (int c = 0; c < 64; c++) {
        float g = 0.f;
        #pragma unroll
        for (int p = 0; p < SPLIT; p++)
            g += partial[((size_t)p * N_GRAPHS + t) * 64 + c];
        s += g * Wl[c];
    }
    out[t] = s / nmax + bl[0];
}

// ---------------- launch ----------------

extern "C" void kernel_launch(void* const* d_in, const int* in_sizes, int n_in,
                              void* d_out, int out_size, void* d_ws, size_t ws_size,
                              hipStream_t stream) {
    const float* x    = (const float*)d_in[0];
    const int*   ei   = (const int*)d_in[1];     // [2, E] int32
    const int*   batch= (const int*)d_in[2];
    const float* W1 = (const float*)d_in[3];  const float* b1 = (const float*)d_in[4];
    const float* W2 = (const float*)d_in[5];  const float* b2 = (const float*)d_in[6];
    const float* W3 = (const float*)d_in[7];  const float* b3 = (const float*)d_in[8];
    const float* W4 = (const float*)d_in[9];  const float* b4 = (const float*)d_in[10];
    const float* Wl = (const float*)d_in[11]; const float* bl = (const float*)d_in[12];
    float* out = (float*)d_out;

    const int* row = ei;
    const int* col = ei + N_EDGES;

    // workspace layout (256B aligned blocks)
    char* ws = (char*)d_ws;
    size_t off = 0;
    auto alloc = [&](size_t bytes) {
        void* p = ws + off;
        off = (off + bytes + 255) & ~(size_t)255;
        return p;
    };
    int*    hist_t  = (int*)alloc((size_t)NB * BLK * 4);
    int*    cursors = (int*)alloc((size_t)NB * BLK * 4);
    int*    bcnt    = (int*)alloc(NB * 4);
    int*    bedges  = (int*)alloc((size_t)NB * CAP * 4);   // aliased by csr
    int*    csr     = bedges;                              // in-place rebuild (safe)
    int*    offs    = (int*)alloc(N_NODES * 4);
    int*    deg_c   = (int*)alloc(N_NODES * 4);
    float*  dinv    = (float*)alloc(N_NODES * 4);
    __half* h16     = (__half*)alloc((size_t)(N_NODES + 1) * 64 * 2);  // fp16 gather table (+1 zero row)
    float*  h_b     = (float*)alloc((size_t)N_NODES * 64 * 4);         // fp32 prop output
    float*  partial = (float*)alloc((size_t)SPLIT * N_GRAPHS * 64 * 4);

    hipMemsetAsync(h16 + (size_t)N_NODES * 64, 0, 64 * 2, stream);   // zero sentinel row

    // CSR build: histogram -> cursors -> bucket scatter -> per-bucket build
    k_hist<<<BLK, 256, 0, stream>>>(col, hist_t);
    k_cursors<<<NB, 512, 0, stream>>>(hist_t, cursors, bcnt);
    k_mid<<<BLK, 256, 0, stream>>>(row, col, cursors, bedges);
    k_build<<<NB, 512, 0, stream>>>(bedges, bcnt, csr, offs, deg_c, dinv);

    const int GB = (N_NODES + 127) / 128;   // 782 gemm blocks
    const int PB = N_NODES / 8;             // 12500 prop blocks (8 nodes/block)

    // layer 1: h16 = fp16(dinv * (x @ W1)) ; h_b = dinv * prop(h16) + b1
    k_gemm<128><<<GB, 256, 0, stream>>>(x, W1, dinv, h16);
    k_prop<<<PB, 256, 0, stream>>>(h16, csr, offs, deg_c, dinv, b1, h_b);
    // layer 2
    k_gemm<64><<<GB, 256, 0, stream>>>(h_b, W2, dinv, h16);
    k_prop<<<PB, 256, 0, stream>>>(h16, csr, offs, deg_c, dinv, b2, h_b);
    // layer 3
    k_gemm<64><<<GB, 256, 0, stream>>>(h_b, W3, dinv, h16);
    k_prop<<<PB, 256, 0, stream>>>(h16, csr, offs, deg_c, dinv, b3, h_b);
    // layer 4
    k_gemm<64><<<GB, 256, 0, stream>>>(h_b, W4, dinv, h16);
    k_prop<<<PB, 256, 0, stream>>>(h16, csr, offs, deg_c, dinv, b4, h_b);

    // pooling + readout (atomic-free)
    k_pool<<<N_GRAPHS * SPLIT, 256, 0, stream>>>(h_b, batch, partial);
    k_final<<<1, 128, 0, stream>>>(partial, batch, Wl, bl, out);
}

// Round 13
// 360.476 us; speedup vs baseline: 1.4106x; 1.0188x over previous
//
#include <hip/hip_runtime.h>
#include <hip/hip_bf16.h>
#include <hip/hip_fp16.h>

// Problem constants (match reference)
#define N_NODES 100000
#define N_EDGES 1600000
#define N_GRAPHS 128

// Counting-sort CSR build parameters
#define BSH 9                 // bucket = col >> 9
#define BNODES 512            // nodes per bucket
#define NB 196                // ceil(100000 / 512)
#define CAP 12288             // static per-bucket csr/record capacity (elems)
#define BLK 512               // histogram blocks
#define EPB (N_EDGES / BLK)   // 3125 edges per block (exact)
#define RECMAX 10240          // max records per bucket held in LDS

#define SPLIT 4               // pooling blocks per graph

typedef __attribute__((ext_vector_type(8))) _Float16 v8h;
typedef __attribute__((ext_vector_type(4))) float v4f;

// ---------------- CSR build (no global atomics) ----------------

__global__ __launch_bounds__(256) void k_hist(const int* __restrict__ col,
                                              int* __restrict__ hist_t) {
    __shared__ int h[NB];
    const int t = threadIdx.x, b = blockIdx.x;
    for (int i = t; i < NB; i += 256) h[i] = 0;
    __syncthreads();
    const int e0 = b * EPB;
    for (int i = t; i < EPB; i += 256) atomicAdd(&h[col[e0 + i] >> BSH], 1);
    __syncthreads();
    for (int i = t; i < NB; i += 256) hist_t[i * BLK + b] = h[i];
}

__global__ __launch_bounds__(512) void k_cursors(const int* __restrict__ hist_t,
                                                 int* __restrict__ cursors,
                                                 int* __restrict__ bcnt) {
    __shared__ int s[BLK];
    const int t = threadIdx.x, bin = blockIdx.x;
    const int v = hist_t[bin * BLK + t];
    s[t] = v; __syncthreads();
    for (int off = 1; off < BLK; off <<= 1) {
        int a = (t >= off) ? s[t - off] : 0;
        __syncthreads(); s[t] += a; __syncthreads();
    }
    cursors[bin * BLK + t] = bin * CAP + s[t] - v;   // exclusive + static base
    if (t == BLK - 1) bcnt[bin] = s[t];
}

__global__ __launch_bounds__(256) void k_mid(const int* __restrict__ row,
                                             const int* __restrict__ col,
                                             const int* __restrict__ cursors,
                                             int* __restrict__ bedges) {
    __shared__ int cur[NB];
    const int t = threadIdx.x, b = blockIdx.x;
    for (int i = t; i < NB; i += 256) cur[i] = cursors[i * BLK + b];
    __syncthreads();
    const int e0 = b * EPB;
    for (int i = t; i < EPB; i += 256) {
        const int c = col[e0 + i];
        const int r = row[e0 + i];
        const int pos = atomicAdd(&cur[c >> BSH], 1);
        bedges[pos] = r | ((c & (BNODES - 1)) << 17);   // row<2^17, lcol 9 bits
    }
}

__global__ __launch_bounds__(512) void k_build(const int* __restrict__ bedges,
                                               const int* __restrict__ bcnt,
                                               int* __restrict__ csr,
                                               int* __restrict__ offs,
                                               int* __restrict__ deg_c,
                                               float* __restrict__ dinv) {
    __shared__ int rec[RECMAX];
    __shared__ int deg[BNODES];
    __shared__ int offx[BNODES];
    __shared__ int cur[BNODES];
    const int t = threadIdx.x, bin = blockIdx.x;
    const int base = bin * CAP;
    const int cnt = bcnt[bin];
    const int vb = bin << BSH;
    const int nn = min(BNODES, N_NODES - vb);
    for (int i = t; i < cnt; i += 512) rec[i] = bedges[base + i];
    deg[t] = 0;
    __syncthreads();                 // all record loads done before any csr write
    for (int i = t; i < cnt; i += 512) atomicAdd(&deg[(rec[i] >> 17) & (BNODES - 1)], 1);
    __syncthreads();
    const int d = (t < nn) ? deg[t] : 0;
    const int pd = (d + 7) & ~7;     // pad each segment to x8 (MLP in k_prop)
    offx[t] = pd; __syncthreads();
    for (int off = 1; off < BNODES; off <<= 1) {
        int a = (t >= off) ? offx[t - off] : 0;
        __syncthreads(); offx[t] += a; __syncthreads();
    }
    const int myoff = offx[t] - pd;  // exclusive
    cur[t] = myoff;
    if (t < nn) {
        offs[vb + t] = base + myoff;
        deg_c[vb + t] = d;
        dinv[vb + t] = (d > 0) ? rsqrtf((float)d) : 0.0f;
        for (int j = d; j < pd; j++) csr[base + myoff + j] = N_NODES;  // sentinel
    }
    __syncthreads();
    for (int i = t; i < cnt; i += 512) {
        const int r = rec[i];
        const int pos = atomicAdd(&cur[(r >> 17) & (BNODES - 1)], 1);
        csr[base + pos] = r & 0x1FFFF;
    }
}

// ---------------- MFMA GEMM: H16[n] = fp16(dinv[n] * (X[n,:] @ W)) ----------------
// 128-node x 64-ch block tile, 4 waves. fp16 inputs, fp32 accumulate; W split
// hi+lo fp16 so weight rounding is ~exact. TIN = float (layer 1) or __half
// (layers 2-4; prop already emitted rounded fp16, so staging is a raw copy).

template <int CIN, typename TIN>
__global__ __launch_bounds__(256) void k_gemm(const TIN* __restrict__ X,
                                              const float* __restrict__ W,
                                              const float* __restrict__ dinv,
                                              __half* __restrict__ H16) {
    constexpr int SA = 72;                       // halves per node row (pad 8)
    constexpr int SB = 72;
    __shared__ __align__(16) _Float16 sA[128 * SA];   // 18.4 KB
    __shared__ __align__(16) _Float16 sBh[64 * SB];   // 9.2 KB
    __shared__ __align__(16) _Float16 sBl[64 * SB];   // 9.2 KB
    const int t = threadIdx.x;
    const int w = t >> 6, lane = t & 63;
    const int quad = lane >> 4, l16 = lane & 15;
    const int nb = blockIdx.x * 128;

    v4f acc[2][4] = {};   // [mtile][ntile]

    for (int k0 = 0; k0 < CIN; k0 += 64) {
        if (k0) __syncthreads();
        // stage W chunk [64k x 64c] -> transposed hi/lo [c][k]
        for (int i = t; i < 64 * 16; i += 256) {
            const int k = i >> 4, c4 = (i & 15) * 4;
            const float4 wv = *reinterpret_cast<const float4*>(W + (size_t)(k0 + k) * 64 + c4);
            const float wf[4] = {wv.x, wv.y, wv.z, wv.w};
            #pragma unroll
            for (int j = 0; j < 4; j++) {
                const _Float16 hi = (_Float16)wf[j];
                sBh[(c4 + j) * SB + k] = hi;
                sBl[(c4 + j) * SB + k] = (_Float16)(wf[j] - (float)hi);
            }
        }
        // stage X chunk [128 nodes x 64k]
        if constexpr (sizeof(TIN) == 4) {         // fp32 -> fp16 convert
            for (int i = t; i < 128 * 16; i += 256) {
                const int node = i >> 4, k4 = (i & 15) * 4;
                const int gn = nb + node;
                float4 v = make_float4(0.f, 0.f, 0.f, 0.f);
                if (gn < N_NODES)
                    v = *reinterpret_cast<const float4*>((const float*)X + (size_t)gn * CIN + k0 + k4);
                _Float16* d = &sA[node * SA + k4];
                d[0] = (_Float16)v.x; d[1] = (_Float16)v.y;
                d[2] = (_Float16)v.z; d[3] = (_Float16)v.w;
            }
        } else {                                   // fp16 raw copy (8 halves/16B)
            for (int i = t; i < 128 * 8; i += 256) {
                const int node = i >> 3, k8 = (i & 7) * 8;
                const int gn = nb + node;
                int4 v = make_int4(0, 0, 0, 0);
                if (gn < N_NODES)
                    v = *reinterpret_cast<const int4*>((const __half*)X + (size_t)gn * CIN + k0 + k8);
                *reinterpret_cast<int4*>(&sA[node * SA + k8]) = v;
            }
        }
        __syncthreads();

        #pragma unroll
        for (int kt = 0; kt < 2; kt++) {
            const int kb = kt * 32 + quad * 8;
            v8h afr[2], bh[4], bl[4];
            #pragma unroll
            for (int mt = 0; mt < 2; mt++)
                afr[mt] = *reinterpret_cast<const v8h*>(&sA[(w * 32 + mt * 16 + l16) * SA + kb]);
            #pragma unroll
            for (int nt = 0; nt < 4; nt++) {
                bh[nt] = *reinterpret_cast<const v8h*>(&sBh[(nt * 16 + l16) * SB + kb]);
                bl[nt] = *reinterpret_cast<const v8h*>(&sBl[(nt * 16 + l16) * SB + kb]);
            }
            #pragma unroll
            for (int mt = 0; mt < 2; mt++)
                #pragma unroll
                for (int nt = 0; nt < 4; nt++) {
                    acc[mt][nt] = __builtin_amdgcn_mfma_f32_16x16x32_f16(afr[mt], bh[nt], acc[mt][nt], 0, 0, 0);
                    acc[mt][nt] = __builtin_amdgcn_mfma_f32_16x16x32_f16(afr[mt], bl[nt], acc[mt][nt], 0, 0, 0);
                }
        }
    }

    // epilogue: D row = quad*4+reg, col = l16
    #pragma unroll
    for (int mt = 0; mt < 2; mt++) {
        #pragma unroll
        for (int reg = 0; reg < 4; reg++) {
            const int node = nb + w * 32 + mt * 16 + quad * 4 + reg;
            if (node < N_NODES) {
                const float dv = dinv[node];
                #pragma unroll
                for (int nt = 0; nt < 4; nt++)
                    H16[(size_t)node * 64 + nt * 16 + l16] =
                        __float2half(acc[mt][nt][reg] * dv);
            }
        }
    }
}

// ---------------- propagation: Hout[v] = dinv[v] * sum_e fp32(H16[row_e]) + bias --------
// 4 NODES PER WAVE, one per 16-lane quarter; lane owns a 4-channel group
// (8 B). Each gather instruction serves 4 edges (one row per quarter);
// 8-deep unroll -> 32 edges in flight per wave. Divergent per-quarter trip
// counts run under the exec mask (idle quarters issue nothing).
// TOUT = __half (layers 1-3: rounding moved here, bit-identical to staging
// in the next GEMM) or float (layer 4, feeds fp32 pooling).

template <typename TOUT>
__global__ __launch_bounds__(256) void k_prop(const __half* __restrict__ Hin,
                                              const int* __restrict__ csr,
                                              const int* __restrict__ offs,
                                              const int* __restrict__ deg_c,
                                              const float* __restrict__ dinv,
                                              const float* __restrict__ bias,
                                              TOUT* __restrict__ Hout) {
    const int wave = threadIdx.x >> 6, lane = threadIdx.x & 63;
    const int quad = lane >> 4;            // node slot within the wave
    const int l = lane & 15;               // channel group: channels 4l..4l+3
    const int v = blockIdx.x * 16 + wave * 4 + quad;   // grid exact: v < N_NODES
    const int start = offs[v];             // multiple of 8 -> 32B aligned
    const int cp = (deg_c[v] + 7) & ~7;
    const int* ep = csr + start;
    const __half* hb = Hin + l * 4;
    float a0 = 0.f, a1 = 0.f, a2 = 0.f, a3 = 0.f;
    for (int j = 0; j < cp; j += 8) {      // per-quarter trip count (exec mask)
        const int4 q0 = *reinterpret_cast<const int4*>(ep + j);
        const int4 q1 = *reinterpret_cast<const int4*>(ep + j + 4);
        const int2 r0 = *reinterpret_cast<const int2*>(hb + (size_t)q0.x * 64);
        const int2 r1 = *reinterpret_cast<const int2*>(hb + (size_t)q0.y * 64);
        const int2 r2 = *reinterpret_cast<const int2*>(hb + (size_t)q0.z * 64);
        const int2 r3 = *reinterpret_cast<const int2*>(hb + (size_t)q0.w * 64);
        const int2 r4 = *reinterpret_cast<const int2*>(hb + (size_t)q1.x * 64);
        const int2 r5 = *reinterpret_cast<const int2*>(hb + (size_t)q1.y * 64);
        const int2 r6 = *reinterpret_cast<const int2*>(hb + (size_t)q1.z * 64);
        const int2 r7 = *reinterpret_cast<const int2*>(hb + (size_t)q1.w * 64);
        #define ACC(r) { \
            const float2 u = __half22float2(*reinterpret_cast<const __half2*>(&r.x)); \
            const float2 w = __half22float2(*reinterpret_cast<const __half2*>(&r.y)); \
            a0 += u.x; a1 += u.y; a2 += w.x; a3 += w.y; }
        ACC(r0) ACC(r1) ACC(r2) ACC(r3) ACC(r4) ACC(r5) ACC(r6) ACC(r7)
        #undef ACC
    }
    const float dv = dinv[v];
    const float4 bs = *reinterpret_cast<const float4*>(bias + l * 4);
    const float o0 = dv * a0 + bs.x, o1 = dv * a1 + bs.y;
    const float o2 = dv * a2 + bs.z, o3 = dv * a3 + bs.w;
    if constexpr (sizeof(TOUT) == 2) {
        __half2 h[2];
        h[0] = __floats2half2_rn(o0, o1);
        h[1] = __floats2half2_rn(o2, o3);
        *reinterpret_cast<int2*>((__half*)Hout + (size_t)v * 64 + l * 4) =
            *reinterpret_cast<const int2*>(h);
    } else {
        float4 o; o.x = o0; o.y = o1; o.z = o2; o.w = o3;
        *reinterpret_cast<float4*>((float*)Hout + (size_t)v * 64 + l * 4) = o;
    }
}

// ---------------- pooling: one (graph, split) block; atomic-free partials ----------------

__global__ __launch_bounds__(256) void k_pool(const float* __restrict__ H,
                                              const int* __restrict__ batch,
                                              float* __restrict__ partial) {
    const int g = blockIdx.x >> 2;           // graph
    const int s = blockIdx.x & (SPLIT - 1);  // split
    int lo = 0, hi = N_NODES;
    while (lo < hi) { int m = (lo + hi) >> 1; if (batch[m] < g) lo = m + 1; else hi = m; }
    const int a = lo;
    lo = 0; hi = N_NODES;
    while (lo < hi) { int m = (lo + hi) >> 1; if (batch[m] < g + 1) lo = m + 1; else hi = m; }
    const int b = lo;

    const int wave = threadIdx.x >> 6, lane = threadIdx.x & 63;
    const int lane16 = s * 4 + wave;         // 0..15: stride position
    float ac0 = 0.f, ac1 = 0.f, ac2 = 0.f, ac3 = 0.f;
    int v = a + lane16;
    for (; v + 48 < b; v += 64) {            // 4 independent loads in flight
        ac0 += H[(size_t)v * 64 + lane];
        ac1 += H[(size_t)(v + 16) * 64 + lane];
        ac2 += H[(size_t)(v + 32) * 64 + lane];
        ac3 += H[(size_t)(v + 48) * 64 + lane];
    }
    for (; v < b; v += 16) ac0 += H[(size_t)v * 64 + lane];
    const float acc = (ac0 + ac1) + (ac2 + ac3);

    __shared__ float red[4][64];
    red[wave][lane] = acc;
    __syncthreads();
    if (wave == 0) {
        const float r = (red[0][lane] + red[1][lane]) + (red[2][lane] + red[3][lane]);
        partial[((size_t)s * N_GRAPHS + g) * 64 + lane] = r;
    }
}

__global__ void k_final(const float* __restrict__ partial, const int* __restrict__ batch,
                        const float* __restrict__ Wl, const float* __restrict__ bl,
                        float* __restrict__ out) {
    __shared__ int scnt[128];
    int t = threadIdx.x;
    int lo = 0, hi = N_NODES;
    while (lo < hi) { int mid = (lo + hi) >> 1; if (batch[mid] < t) lo = mid + 1; else hi = mid; }
    int a = lo;
    lo = 0; hi = N_NODES;
    while (lo < hi) { int mid = (lo + hi) >> 1; if (batch[mid] < t + 1) lo = mid + 1; else hi = mid; }
    scnt[t] = lo - a;
    __syncthreads();
    for (int off = 64; off > 0; off >>= 1) {
        if (t < off) scnt[t] = max(scnt[t], scnt[t + off]);
        __syncthreads();
    }
    const float nmax = (float)scnt[0];
    float s = 0.f;
    for (int c = 0; c < 64; c++) {
        float g = 0.f;
        #pragma unroll
        for (int p = 0; p < SPLIT; p++)
            g += partial[((size_t)p * N_GRAPHS + t) * 64 + c];
        s += g * Wl[c];
    }
    out[t] = s / nmax + bl[0];
}

// ---------------- launch ----------------

extern "C" void kernel_launch(void* const* d_in, const int* in_sizes, int n_in,
                              void* d_out, int out_size, void* d_ws, size_t ws_size,
                              hipStream_t stream) {
    const float* x    = (const float*)d_in[0];
    const int*   ei   = (const int*)d_in[1];     // [2, E] int32
    const int*   batch= (const int*)d_in[2];
    const float* W1 = (const float*)d_in[3];  const float* b1 = (const float*)d_in[4];
    const float* W2 = (const float*)d_in[5];  const float* b2 = (const float*)d_in[6];
    const float* W3 = (const float*)d_in[7];  const float* b3 = (const float*)d_in[8];
    const float* W4 = (const float*)d_in[9];  const float* b4 = (const float*)d_in[10];
    const float* Wl = (const float*)d_in[11]; const float* bl = (const float*)d_in[12];
    float* out = (float*)d_out;

    const int* row = ei;
    const int* col = ei + N_EDGES;

    // workspace layout (256B aligned blocks)
    char* ws = (char*)d_ws;
    size_t off = 0;
    auto alloc = [&](size_t bytes) {
        void* p = ws + off;
        off = (off + bytes + 255) & ~(size_t)255;
        return p;
    };
    int*    hist_t  = (int*)alloc((size_t)NB * BLK * 4);
    int*    cursors = (int*)alloc((size_t)NB * BLK * 4);
    int*    bcnt    = (int*)alloc(NB * 4);
    int*    bedges  = (int*)alloc((size_t)NB * CAP * 4);   // aliased by csr
    int*    csr     = bedges;                              // in-place rebuild (safe)
    int*    offs    = (int*)alloc(N_NODES * 4);
    int*    deg_c   = (int*)alloc(N_NODES * 4);
    float*  dinv    = (float*)alloc(N_NODES * 4);
    __half* h16     = (__half*)alloc((size_t)(N_NODES + 1) * 64 * 2);  // fp16 gather table (+1 zero row)
    __half* h_c     = (__half*)alloc((size_t)N_NODES * 64 * 2);        // fp16 prop output (layers 1-3)
    float*  h_b     = (float*)alloc((size_t)N_NODES * 64 * 4);         // fp32 prop output (layer 4)
    float*  partial = (float*)alloc((size_t)SPLIT * N_GRAPHS * 64 * 4);

    hipMemsetAsync(h16 + (size_t)N_NODES * 64, 0, 64 * 2, stream);   // zero sentinel row

    // CSR build: histogram -> cursors -> bucket scatter -> per-bucket build
    k_hist<<<BLK, 256, 0, stream>>>(col, hist_t);
    k_cursors<<<NB, 512, 0, stream>>>(hist_t, cursors, bcnt);
    k_mid<<<BLK, 256, 0, stream>>>(row, col, cursors, bedges);
    k_build<<<NB, 512, 0, stream>>>(bedges, bcnt, csr, offs, deg_c, dinv);

    const int GB = (N_NODES + 127) / 128;   // 782 gemm blocks
    const int PB = N_NODES / 16;            // 6250 prop blocks (16 nodes/block)

    // layer 1: h16 = fp16(dinv * (x @ W1)) ; h_c = fp16(dinv * prop(h16) + b1)
    k_gemm<128, float><<<GB, 256, 0, stream>>>(x, W1, dinv, h16);
    k_prop<__half><<<PB, 256, 0, stream>>>(h16, csr, offs, deg_c, dinv, b1, h_c);
    // layer 2
    k_gemm<64, __half><<<GB, 256, 0, stream>>>(h_c, W2, dinv, h16);
    k_prop<__half><<<PB, 256, 0, stream>>>(h16, csr, offs, deg_c, dinv, b2, h_c);
    // layer 3
    k_gemm<64, __half><<<GB, 256, 0, stream>>>(h_c, W3, dinv, h16);
    k_prop<__half><<<PB, 256, 0, stream>>>(h16, csr, offs, deg_c, dinv, b3, h_c);
    // layer 4: fp32 output for pooling
    k_gemm<64, __half><<<GB, 256, 0, stream>>>(h_c, W4, dinv, h16);
    k_prop<float><<<PB, 256, 0, stream>>>(h16, csr, offs, deg_c, dinv, b4, h_b);

    // pooling + readout (atomic-free)
    k_pool<<<N_GRAPHS * SPLIT, 256, 0, stream>>>(h_b, batch, partial);
    k_final<<<1, 128, 0, stream>>>(partial, batch, Wl, bl, out);
}